// Round 9
// baseline (154.007 us; speedup 1.0000x reference)
//
#include <hip/hip_runtime.h>

typedef __attribute__((ext_vector_type(8))) short bf16x8;
typedef __attribute__((ext_vector_type(4))) float f32x4;
typedef __attribute__((ext_vector_type(16))) float f32x16;
typedef unsigned short u16;
typedef unsigned int u32;
typedef __attribute__((ext_vector_type(4))) unsigned int u32x4;

#define DEV static __device__ __forceinline__

DEV u16 f2bf(float f) {
  u32 u = __float_as_uint(f);
  u += 0x7FFFu + ((u >> 16) & 1u);
  return (u16)(u >> 16);
}
DEV float bf2f(u16 h) { return __uint_as_float(((u32)h) << 16); }

DEV void gload16(const void* g, void* l) {
  __builtin_amdgcn_global_load_lds((const __attribute__((address_space(1))) void*)g,
                                   (__attribute__((address_space(3))) void*)l, 16, 0, 0);
}

#define MFMA16(a, b, c) __builtin_amdgcn_mfma_f32_16x16x32_bf16((a), (b), (c), 0, 0, 0)
#define MFMA32(a, b, c) __builtin_amdgcn_mfma_f32_32x32x16_bf16((a), (b), (c), 0, 0, 0)

DEV u32 cvtpk(float lo, float hi) {
  u32 r;
  asm("v_cvt_pk_bf16_f32 %0, %1, %2" : "=v"(r) : "v"(lo), "v"(hi));
  return r;
}
DEV void plswap(u32& a, u32& b) {
  asm volatile("v_permlane32_swap_b32 %0, %1" : "+v"(a), "+v"(b));
}
DEV bf16x8 asbf(u32x4 v) {
  union { u32x4 u; bf16x8 b; } x;
  x.u = v;
  return x.b;
}

// raw barrier with compiler fences: no implicit vmcnt drain (unlike __syncthreads)
DEV void rawbar() {
  __builtin_amdgcn_sched_barrier(0);
  asm volatile("" ::: "memory");
  __builtin_amdgcn_s_barrier();
  asm volatile("" ::: "memory");
  __builtin_amdgcn_sched_barrier(0);
}
#define VMCNT4() asm volatile("s_waitcnt vmcnt(4)" ::: "memory")
#define VMCNT0() asm volatile("s_waitcnt vmcnt(0)" ::: "memory")
#define LGKM0()  asm volatile("s_waitcnt lgkmcnt(0)" ::: "memory")

#define LOG2E 1.4426950408889634f

// ---------------- fp32 -> bf16 convert (x) ----------------
__global__ __launch_bounds__(256) void k_cvt_bf16(const float* __restrict__ in,
                                                  u16* __restrict__ out, int n8) {
  int i = blockIdx.x * 256 + threadIdx.x;
  if (i >= n8) return;
  const f32x4* p = (const f32x4*)(in + (size_t)i * 8);
  f32x4 a = p[0], b = p[1];
  bf16x8 o;
  o[0] = (short)f2bf(a[0]); o[1] = (short)f2bf(a[1]);
  o[2] = (short)f2bf(a[2]); o[3] = (short)f2bf(a[3]);
  o[4] = (short)f2bf(b[0]); o[5] = (short)f2bf(b[1]);
  o[6] = (short)f2bf(b[2]); o[7] = (short)f2bf(b[3]);
  *(bf16x8*)(out + (size_t)i * 8) = o;
}

// ---------------- fp32 [rows][cols] -> bf16 [cols][rows] ----------------
__global__ __launch_bounds__(256) void k_transpose_bf16(const float* __restrict__ src,
                                                        u16* __restrict__ dst,
                                                        int rows, int cols) {
  __shared__ u16 lds[64][72];
  int t = threadIdx.x;
  int r0 = blockIdx.y * 64, c0 = blockIdx.x * 64;
  int r = t >> 2, cq = (t & 3) << 4;
  const float* s = src + (size_t)(r0 + r) * cols + c0 + cq;
#pragma unroll
  for (int i = 0; i < 16; i += 4) {
    f32x4 v = *(const f32x4*)(s + i);
    lds[r][cq + i + 0] = f2bf(v[0]);
    lds[r][cq + i + 1] = f2bf(v[1]);
    lds[r][cq + i + 2] = f2bf(v[2]);
    lds[r][cq + i + 3] = f2bf(v[3]);
  }
  __syncthreads();
  int c = t >> 2, rq = (t & 3) << 4;
  bf16x8 o0, o1;
#pragma unroll
  for (int i = 0; i < 8; ++i) o0[i] = (short)lds[rq + i][c];
#pragma unroll
  for (int i = 0; i < 8; ++i) o1[i] = (short)lds[rq + 8 + i][c];
  u16* d = dst + (size_t)(c0 + c) * rows + r0 + rq;
  *(bf16x8*)d = o0;
  *(bf16x8*)(d + 8) = o1;
}

// ---------------- bf16 GEMM: C[M][N] = A[M][K] * Bt[N][K]^T ----------------
// 1D grid with bijective XCD swizzle (nwg % 8 == 0): wg = (orig&7)*(nwg/8) + orig/8.
template <bool OUT_BF16, bool HAS_BIAS>
__global__ __launch_bounds__(256) void k_gemm_bt(const u16* __restrict__ A,
                                                 const u16* __restrict__ Bt,
                                                 void* __restrict__ Cout,
                                                 const float* __restrict__ bias,
                                                 int M, int N, int K, int nbx) {
  __shared__ __align__(16) u16 lsA[128 * 32];
  __shared__ __align__(16) u16 lsB[128 * 32];
  int tid = threadIdx.x;
  int lane = tid & 63, wave = tid >> 6;
  int wr = (wave >> 1) * 64, wc = (wave & 1) * 64;
  int nwg = gridDim.x;
  int orig = blockIdx.x;
  int wg = (orig & 7) * (nwg >> 3) + (orig >> 3);
  int bm = (wg / nbx) * 128, bn = (wg % nbx) * 128;

  f32x4 acc[4][4] = {};

  const u16* aSrc[2]; u16* aDst[2];
  const u16* bSrc[2]; u16* bDst[2];
#pragma unroll
  for (int j = 0; j < 2; ++j) {
    int s = wave * 128 + j * 64 + lane;
    int row = s >> 2, chunk = s & 3;
    int g = chunk ^ ((row >> 1) & 3);
    aSrc[j] = A + (size_t)(bm + row) * K + g * 8;
    bSrc[j] = Bt + (size_t)(bn + row) * K + g * 8;
    aDst[j] = &lsA[(wave * 128 + j * 64) * 8];
    bDst[j] = &lsB[(wave * 128 + j * 64) * 8];
  }

  for (int k0 = 0; k0 < K; k0 += 32) {
    __syncthreads();
    gload16(aSrc[0] + k0, aDst[0]);
    gload16(aSrc[1] + k0, aDst[1]);
    gload16(bSrc[0] + k0, bDst[0]);
    gload16(bSrc[1] + k0, bDst[1]);
    __syncthreads();
    bf16x8 af[4], bfr[4];
#pragma unroll
    for (int m = 0; m < 4; ++m) {
      int r = wr + m * 16 + (lane & 15);
      int p = (lane >> 4) ^ ((r >> 1) & 3);
      af[m] = *(const bf16x8*)&lsA[r * 32 + p * 8];
    }
#pragma unroll
    for (int n = 0; n < 4; ++n) {
      int r = wc + n * 16 + (lane & 15);
      int p = (lane >> 4) ^ ((r >> 1) & 3);
      bfr[n] = *(const bf16x8*)&lsB[r * 32 + p * 8];
    }
#pragma unroll
    for (int m = 0; m < 4; ++m)
#pragma unroll
      for (int n = 0; n < 4; ++n)
        acc[m][n] = MFMA16(af[m], bfr[n], acc[m][n]);
  }

#pragma unroll
  for (int m = 0; m < 4; ++m) {
    int row = bm + wr + m * 16 + ((lane >> 4) << 2);
#pragma unroll
    for (int n = 0; n < 4; ++n) {
      int col = bn + wc + n * 16 + (lane & 15);
#pragma unroll
      for (int j = 0; j < 4; ++j) {
        if (OUT_BF16) {
          ((u16*)Cout)[(size_t)(row + j) * N + col] = f2bf(acc[m][n][j]);
        } else {
          float bb = HAS_BIAS ? bias[col] : 0.f;
          ((float*)Cout)[(size_t)(row + j) * N + col] = acc[m][n][j] + bb;
        }
      }
    }
  }
}

// ---------------- repack: normalize q,k (fold scale*log2e into q), transpose v ----------------
__global__ __launch_bounds__(256) void k_repack(const u16* __restrict__ QKV,
                                                const float* __restrict__ logit_scale,
                                                u16* __restrict__ Qn, u16* __restrict__ Kn,
                                                u16* __restrict__ Vt) {
  int nt = blockIdx.x;  // 0..31 (64-row tile)
  int h = blockIdx.y;   // 0..15
  int b = blockIdx.z;   // 0..1
  int tid = threadIdx.x;
  int lane = tid & 63, wave = tid >> 6;
  int bh = b * 16 + h;
  float scale = __expf(fminf(logit_scale[h], 4.6051701859880914f)) * LOG2E;

#pragma unroll 1
  for (int i = 0; i < 16; ++i) {
    int n = nt * 64 + wave * 16 + i;
    size_t off = ((size_t)(b * 2048 + n)) * 3072 + h * 64 + lane;
    float q = bf2f(QKV[off]);
    float k = bf2f(QKV[off + 1024]);
    float sq = q * q, sk = k * k;
#pragma unroll
    for (int d = 1; d < 64; d <<= 1) {
      sq += __shfl_xor(sq, d, 64);
      sk += __shfl_xor(sk, d, 64);
    }
    float rq = scale / fmaxf(sqrtf(sq), 1e-12f);
    float rk = 1.0f / fmaxf(sqrtf(sk), 1e-12f);
    size_t o2 = ((size_t)bh * 2048 + n) * 64 + lane;
    Qn[o2] = f2bf(q * rq);
    Kn[o2] = f2bf(k * rk);
  }

  // V transpose via LDS
  __shared__ u16 lds[64][72];
  int r = tid >> 2, cq = (tid & 3) << 4;
  size_t voff = ((size_t)(b * 2048 + nt * 64 + r)) * 3072 + 2048 + h * 64 + cq;
  *(bf16x8*)&lds[r][cq] = *(const bf16x8*)&QKV[voff];
  *(bf16x8*)&lds[r][cq + 8] = *(const bf16x8*)&QKV[voff + 8];
  __syncthreads();
  int d = tid >> 2, nq = (tid & 3) << 4;
  bf16x8 o0, o1;
#pragma unroll
  for (int i = 0; i < 8; ++i) o0[i] = (short)lds[nq + i][d];
#pragma unroll
  for (int i = 0; i < 8; ++i) o1[i] = (short)lds[nq + 8 + i][d];
  u16* vd = Vt + ((size_t)bh * 64 + d) * 2048 + nt * 64 + nq;
  *(bf16x8*)vd = o0;
  *(bf16x8*)(vd + 8) = o1;
}

// ---------------- flash attention (cross-tile pipelined: QK[t] MFMA || exp/pack[t-1] VALU) ----------------
// Per iter: buf[cur] ready -> stage(t+1) -> QK MFMA for tile t (matrix pipe) while VALU
// finishes softmax of tile t-1 -> PV(t-1) from registers -> reload V[t] frags to regs ->
// lgkmcnt(0) -> barrier. P = 2^(S'-scale') via exp2f (LOG2E folded into Qn in repack).
// No split-KV (R2/R4 showed combine is net-negative). grid (bh=32, qblk=16); blockIdx.x=bh
// pins each head's blocks to one XCD (K/V L2-resident).
__global__ __launch_bounds__(256, 2) void k_flash(const u16* __restrict__ Qn,
                                                  const u16* __restrict__ Kn,
                                                  const u16* __restrict__ Vt,
                                                  const float* __restrict__ logit_scale,
                                                  u16* __restrict__ AO) {
  __shared__ __align__(16) u16 lsK[2][64 * 64];
  __shared__ __align__(16) u16 lsV[2][64 * 64];
  __shared__ float l_s[4][32];
  int tid = threadIdx.x, lane = tid & 63, wave = tid >> 6;
  int r31 = lane & 31, h = lane >> 5;
  int bh = blockIdx.x, b = bh >> 4, hd = bh & 15;
  int qw = blockIdx.y * 128 + wave * 32;
  const u16* Q = Qn + (size_t)bh * 2048 * 64;
  const u16* Kb = Kn + (size_t)bh * 2048 * 64;
  const u16* Vb = Vt + (size_t)bh * 64 * 2048;

  float negC = -__expf(fminf(logit_scale[hd], 4.6051701859880914f)) * LOG2E;

  // Q B-fragments: col=lane&31=q, k(d) = 16*ks + 8*h + e
  bf16x8 qB[4];
#pragma unroll
  for (int ks = 0; ks < 4; ++ks)
    qB[ks] = *(const bf16x8*)&Q[(size_t)(qw + r31) * 64 + ks * 16 + h * 8];

  // staging offsets (pre-swizzled global source, linear LDS dest)
  size_t kGO[2], vGO[2];
  int lOff[2];
#pragma unroll
  for (int j = 0; j < 2; ++j) {
    int s = j * 256 + tid;
    int row = s >> 3, ch = s & 7, g = ch ^ (row & 7);
    kGO[j] = (size_t)row * 64 + g * 8;
    vGO[j] = (size_t)row * 2048 + g * 8;
    lOff[j] = s * 8;
  }

  // LDS read offsets (swizzled): rows a*32+r31, chunk (2*ks+h) ^ (r31&7)
  int off[2][4];
#pragma unroll
  for (int a = 0; a < 2; ++a)
#pragma unroll
    for (int ks = 0; ks < 4; ++ks)
      off[a][ks] = (a * 32 + r31) * 64 + ((((ks << 1) | h) ^ (r31 & 7)) << 3);

  f32x16 o0, o1;
#pragma unroll
  for (int i = 0; i < 16; ++i) { o0[i] = 0.f; o1[i] = 0.f; }
  float lsum = 0.f;

  f32x16 sA0, sA1, sB0, sB1;   // two-tile S state (pipeline)
  bf16x8 vf[8];                // V fragments of current tile (consumed next iter)

#define STAGE(dstbuf, kvt)                                          \
  {                                                                 \
    size_t kv0 = (size_t)(kvt) * 64;                                \
    gload16(Kb + kv0 * 64 + kGO[0], &lsK[dstbuf][lOff[0]]);         \
    gload16(Kb + kv0 * 64 + kGO[1], &lsK[dstbuf][lOff[1]]);         \
    gload16(Vb + kv0 + vGO[0], &lsV[dstbuf][lOff[0]]);              \
    gload16(Vb + kv0 + vGO[1], &lsV[dstbuf][lOff[1]]);              \
  }

#define QK(SN0, SN1, CUR)                                           \
  {                                                                 \
    bf16x8 k0f[4], k1f[4];                                          \
    _Pragma("unroll") for (int ks = 0; ks < 4; ++ks) {              \
      k0f[ks] = *(const bf16x8*)&lsK[CUR][off[0][ks]];              \
      k1f[ks] = *(const bf16x8*)&lsK[CUR][off[1][ks]];              \
    }                                                               \
    _Pragma("unroll") for (int i = 0; i < 16; ++i) { SN0[i] = negC; SN1[i] = negC; } \
    __builtin_amdgcn_s_setprio(1);                                  \
    _Pragma("unroll") for (int ks = 0; ks < 4; ++ks) {              \
      SN0 = MFMA32(k0f[ks], qB[ks], SN0);                           \
      SN1 = MFMA32(k1f[ks], qB[ks], SN1);                           \
    }                                                               \
    __builtin_amdgcn_s_setprio(0);                                  \
  }

#define FINISH_PV(SP0, SP1)                                         \
  {                                                                 \
    _Pragma("unroll") for (int i = 0; i < 16; ++i) {                \
      float e0 = exp2f(SP0[i]);                                     \
      float e1 = exp2f(SP1[i]);                                     \
      lsum += e0 + e1;                                              \
      SP0[i] = e0; SP1[i] = e1;                                     \
    }                                                               \
    bf16x8 pa[4];                                                   \
    {                                                               \
      u32 c0 = cvtpk(SP0[0], SP0[1]),  c1 = cvtpk(SP0[2], SP0[3]);  \
      u32 c2 = cvtpk(SP0[4], SP0[5]),  c3 = cvtpk(SP0[6], SP0[7]);  \
      u32 c4 = cvtpk(SP0[8], SP0[9]),  c5 = cvtpk(SP0[10], SP0[11]);\
      u32 c6 = cvtpk(SP0[12], SP0[13]), c7 = cvtpk(SP0[14], SP0[15]);\
      plswap(c0, c2); plswap(c1, c3); plswap(c4, c6); plswap(c5, c7);\
      pa[0] = asbf((u32x4){c0, c1, c2, c3});                        \
      pa[1] = asbf((u32x4){c4, c5, c6, c7});                        \
      u32 d0 = cvtpk(SP1[0], SP1[1]),  d1 = cvtpk(SP1[2], SP1[3]);  \
      u32 d2 = cvtpk(SP1[4], SP1[5]),  d3 = cvtpk(SP1[6], SP1[7]);  \
      u32 d4 = cvtpk(SP1[8], SP1[9]),  d5 = cvtpk(SP1[10], SP1[11]);\
      u32 d6 = cvtpk(SP1[12], SP1[13]), d7 = cvtpk(SP1[14], SP1[15]);\
      plswap(d0, d2); plswap(d1, d3); plswap(d4, d6); plswap(d5, d7);\
      pa[2] = asbf((u32x4){d0, d1, d2, d3});                        \
      pa[3] = asbf((u32x4){d4, d5, d6, d7});                        \
    }                                                               \
    __builtin_amdgcn_s_setprio(1);                                  \
    _Pragma("unroll") for (int ks = 0; ks < 4; ++ks) {              \
      o0 = MFMA32(pa[ks], vf[ks], o0);                              \
      o1 = MFMA32(pa[ks], vf[ks + 4], o1);                          \
    }                                                               \
    __builtin_amdgcn_s_setprio(0);                                  \
  }

#define VLOAD(CUR)                                                  \
  {                                                                 \
    _Pragma("unroll") for (int ks = 0; ks < 4; ++ks) {              \
      vf[ks] = *(const bf16x8*)&lsV[CUR][off[0][ks]];               \
      vf[ks + 4] = *(const bf16x8*)&lsV[CUR][off[1][ks]];           \
    }                                                               \
  }

  // prologue: stage tile 0; peel iter 0 (no prev to finish)
  STAGE(0, 0);
  STAGE(1, 1);
  VMCNT4();
  rawbar();
  QK(sA0, sA1, 0);
  VLOAD(0);
  LGKM0();
  rawbar();

#pragma unroll 1
  for (int t = 1; t < 31; t += 2) {
    // iter t (odd): cur=1, SN=B, SP=A
    STAGE(0, t + 1);
    VMCNT4();
    rawbar();
    QK(sB0, sB1, 1);
    FINISH_PV(sA0, sA1);   // exp/pack tile t-1 overlaps QK MFMAs; PV uses vf (tile t-1)
    VLOAD(1);              // reload vf with tile t's V
    LGKM0();
    rawbar();
    // iter t+1 (even): cur=0, SN=A, SP=B
    if (t + 1 < 31) {
      STAGE(1, t + 2);
      VMCNT4();
    } else {
      VMCNT0();
    }
    rawbar();
    QK(sA0, sA1, 0);
    FINISH_PV(sB0, sB1);
    VLOAD(0);
    LGKM0();
    rawbar();
  }
  // iter 31: cur=1, SN=B, SP=A; nothing left to stage
  VMCNT0();
  rawbar();
  QK(sB0, sB1, 1);
  FINISH_PV(sA0, sA1);
  VLOAD(1);
  LGKM0();
  rawbar();
  // epilogue: finish tile 31
  FINISH_PV(sB0, sB1);

#undef STAGE
#undef QK
#undef FINISH_PV
#undef VLOAD

  // combine l across lane halves; redistribute per-q 1/l via LDS
  float ltot = lsum + __shfl_xor(lsum, 32, 64);
  if (h == 0) l_s[wave][r31] = 1.0f / ltot;
  __syncthreads();

#pragma unroll
  for (int r = 0; r < 16; ++r) {
    int cr = (r & 3) + ((r >> 2) << 3) + (h << 2);
    int qr = qw + cr;
    float li = l_s[wave][cr];
    size_t base = ((size_t)(b * 2048 + qr)) * 1024 + hd * 64;
    AO[base + r31] = f2bf(o0[r] * li);
    AO[base + 32 + r31] = f2bf(o1[r] * li);
  }
}

// ---------------- host ----------------
extern "C" void kernel_launch(void* const* d_in, const int* in_sizes, int n_in,
                              void* d_out, int out_size, void* d_ws, size_t ws_size,
                              hipStream_t stream) {
  const float* x = (const float*)d_in[0];
  const float* w_qkv = (const float*)d_in[1];
  const float* w_out = (const float*)d_in[2];
  const float* b_out = (const float*)d_in[3];
  const float* logit_scale = (const float*)d_in[4];

  char* ws = (char*)d_ws;
  u16* Xbf   = (u16*)(ws);                   // 8 MB  [4096][1024]
  u16* Wqkvt = (u16*)(ws + (8ll << 20));     // 6 MB  [3072][1024]
  u16* Woutt = (u16*)(ws + (14ll << 20));    // 2 MB  [1024][1024]
  u16* QKV   = (u16*)(ws + (16ll << 20));    // 24 MB [4096][3072]
  u16* Qn    = (u16*)(ws + (40ll << 20));    // 8 MB  [2][16][2048][64]
  u16* Kn    = (u16*)(ws + (48ll << 20));    // 8 MB
  u16* Vt    = (u16*)(ws + (56ll << 20));    // 8 MB  [2][16][64][2048]
  u16* AO    = Xbf;                          // reuse x-bf16 region [4096][1024]
  float* out = (float*)d_out;

  k_cvt_bf16<<<2048, 256, 0, stream>>>(x, Xbf, 524288);
  k_transpose_bf16<<<dim3(48, 16), 256, 0, stream>>>(w_qkv, Wqkvt, 1024, 3072);
  k_transpose_bf16<<<dim3(16, 16), 256, 0, stream>>>(w_out, Woutt, 1024, 1024);
  k_gemm_bt<true, false><<<768, 256, 0, stream>>>(Xbf, Wqkvt, QKV, nullptr,
                                                  4096, 3072, 1024, 24);
  k_repack<<<dim3(32, 16, 2), 256, 0, stream>>>(QKV, logit_scale, Qn, Kn, Vt);
  k_flash<<<dim3(32, 16), 256, 0, stream>>>(Qn, Kn, Vt, logit_scale, AO);
  k_gemm_bt<false, true><<<256, 256, 0, stream>>>(AO, Woutt, out, b_out,
                                                  4096, 1024, 1024, 8);
}

// Round 10
// 136.168 us; speedup vs baseline: 1.1310x; 1.1310x over previous
//
#include <hip/hip_runtime.h>

typedef __attribute__((ext_vector_type(8))) short bf16x8;
typedef __attribute__((ext_vector_type(4))) float f32x4;
typedef __attribute__((ext_vector_type(16))) float f32x16;
typedef unsigned short u16;
typedef unsigned int u32;
typedef __attribute__((ext_vector_type(4))) unsigned int u32x4;

#define DEV static __device__ __forceinline__

DEV u16 f2bf(float f) {
  u32 u = __float_as_uint(f);
  u += 0x7FFFu + ((u >> 16) & 1u);
  return (u16)(u >> 16);
}
DEV float bf2f(u16 h) { return __uint_as_float(((u32)h) << 16); }

DEV void gload16(const void* g, void* l) {
  __builtin_amdgcn_global_load_lds((const __attribute__((address_space(1))) void*)g,
                                   (__attribute__((address_space(3))) void*)l, 16, 0, 0);
}

#define MFMA16(a, b, c) __builtin_amdgcn_mfma_f32_16x16x32_bf16((a), (b), (c), 0, 0, 0)
#define MFMA32(a, b, c) __builtin_amdgcn_mfma_f32_32x32x16_bf16((a), (b), (c), 0, 0, 0)

DEV u32 cvtpk(float lo, float hi) {
  u32 r;
  asm("v_cvt_pk_bf16_f32 %0, %1, %2" : "=v"(r) : "v"(lo), "v"(hi));
  return r;
}
DEV void plswap(u32& a, u32& b) {
  asm volatile("v_permlane32_swap_b32 %0, %1" : "+v"(a), "+v"(b));
}
DEV bf16x8 asbf(u32x4 v) {
  union { u32x4 u; bf16x8 b; } x;
  x.u = v;
  return x.b;
}

// raw barrier with compiler fences: no implicit vmcnt drain (unlike __syncthreads)
DEV void rawbar() {
  __builtin_amdgcn_sched_barrier(0);
  asm volatile("" ::: "memory");
  __builtin_amdgcn_s_barrier();
  asm volatile("" ::: "memory");
  __builtin_amdgcn_sched_barrier(0);
}
#define VMCNT4() asm volatile("s_waitcnt vmcnt(4)" ::: "memory")
#define VMCNT0() asm volatile("s_waitcnt vmcnt(0)" ::: "memory")

#define MAXLOG 4.6051701859880914f

// ---------------- prep: x->bf16 cvt + both weight transposes (merged, 1 launch) ----------------
__global__ __launch_bounds__(256) void k_prep(const float* __restrict__ x,
                                              u16* __restrict__ Xbf,
                                              const float* __restrict__ w_qkv,
                                              u16* __restrict__ Wqkvt,
                                              const float* __restrict__ w_out,
                                              u16* __restrict__ Woutt) {
  __shared__ u16 lds[64][72];
  int blk = blockIdx.x;
  int t = threadIdx.x;
  if (blk < 2048) {
    // cvt: 2048 blocks x 256 thr x 8 elems = 4M elems
    int i = blk * 256 + t;
    const f32x4* p = (const f32x4*)(x + (size_t)i * 8);
    f32x4 a = p[0], b = p[1];
    bf16x8 o;
    o[0] = (short)f2bf(a[0]); o[1] = (short)f2bf(a[1]);
    o[2] = (short)f2bf(a[2]); o[3] = (short)f2bf(a[3]);
    o[4] = (short)f2bf(b[0]); o[5] = (short)f2bf(b[1]);
    o[6] = (short)f2bf(b[2]); o[7] = (short)f2bf(b[3]);
    *(bf16x8*)(Xbf + (size_t)i * 8) = o;
    return;
  }
  // transpose tiles
  const float* src;
  u16* dst;
  int rows, cols, bx, by;
  if (blk < 2816) {
    int q = blk - 2048;          // 768 tiles: w_qkv 1024x3072 -> 3072x1024
    src = w_qkv; dst = Wqkvt; rows = 1024; cols = 3072;
    bx = q % 48; by = q / 48;
  } else {
    int q = blk - 2816;          // 256 tiles: w_out 1024x1024 -> 1024x1024
    src = w_out; dst = Woutt; rows = 1024; cols = 1024;
    bx = q % 16; by = q / 16;
  }
  int r0 = by * 64, c0 = bx * 64;
  int r = t >> 2, cq = (t & 3) << 4;
  const float* s = src + (size_t)(r0 + r) * cols + c0 + cq;
#pragma unroll
  for (int i = 0; i < 16; i += 4) {
    f32x4 v = *(const f32x4*)(s + i);
    lds[r][cq + i + 0] = f2bf(v[0]);
    lds[r][cq + i + 1] = f2bf(v[1]);
    lds[r][cq + i + 2] = f2bf(v[2]);
    lds[r][cq + i + 3] = f2bf(v[3]);
  }
  __syncthreads();
  int c = t >> 2, rq = (t & 3) << 4;
  bf16x8 o0, o1;
#pragma unroll
  for (int i = 0; i < 8; ++i) o0[i] = (short)lds[rq + i][c];
#pragma unroll
  for (int i = 0; i < 8; ++i) o1[i] = (short)lds[rq + 8 + i][c];
  u16* d = dst + (size_t)(c0 + c) * rows + r0 + rq;
  *(bf16x8*)d = o0;
  *(bf16x8*)(d + 8) = o1;
}

// ---------------- bf16 GEMM: C[M][N] = A[M][K] * Bt[N][K]^T ----------------
// 1D grid with bijective XCD swizzle (nwg % 8 == 0): wg = (orig&7)*(nwg/8) + orig/8.
template <bool OUT_BF16, bool HAS_BIAS>
__global__ __launch_bounds__(256) void k_gemm_bt(const u16* __restrict__ A,
                                                 const u16* __restrict__ Bt,
                                                 void* __restrict__ Cout,
                                                 const float* __restrict__ bias,
                                                 int M, int N, int K, int nbx) {
  __shared__ __align__(16) u16 lsA[128 * 32];
  __shared__ __align__(16) u16 lsB[128 * 32];
  int tid = threadIdx.x;
  int lane = tid & 63, wave = tid >> 6;
  int wr = (wave >> 1) * 64, wc = (wave & 1) * 64;
  int nwg = gridDim.x;
  int orig = blockIdx.x;
  int wg = (orig & 7) * (nwg >> 3) + (orig >> 3);
  int bm = (wg / nbx) * 128, bn = (wg % nbx) * 128;

  f32x4 acc[4][4] = {};

  const u16* aSrc[2]; u16* aDst[2];
  const u16* bSrc[2]; u16* bDst[2];
#pragma unroll
  for (int j = 0; j < 2; ++j) {
    int s = wave * 128 + j * 64 + lane;
    int row = s >> 2, chunk = s & 3;
    int g = chunk ^ ((row >> 1) & 3);
    aSrc[j] = A + (size_t)(bm + row) * K + g * 8;
    bSrc[j] = Bt + (size_t)(bn + row) * K + g * 8;
    aDst[j] = &lsA[(wave * 128 + j * 64) * 8];
    bDst[j] = &lsB[(wave * 128 + j * 64) * 8];
  }

  for (int k0 = 0; k0 < K; k0 += 32) {
    __syncthreads();
    gload16(aSrc[0] + k0, aDst[0]);
    gload16(aSrc[1] + k0, aDst[1]);
    gload16(bSrc[0] + k0, bDst[0]);
    gload16(bSrc[1] + k0, bDst[1]);
    __syncthreads();
    bf16x8 af[4], bfr[4];
#pragma unroll
    for (int m = 0; m < 4; ++m) {
      int r = wr + m * 16 + (lane & 15);
      int p = (lane >> 4) ^ ((r >> 1) & 3);
      af[m] = *(const bf16x8*)&lsA[r * 32 + p * 8];
    }
#pragma unroll
    for (int n = 0; n < 4; ++n) {
      int r = wc + n * 16 + (lane & 15);
      int p = (lane >> 4) ^ ((r >> 1) & 3);
      bfr[n] = *(const bf16x8*)&lsB[r * 32 + p * 8];
    }
#pragma unroll
    for (int m = 0; m < 4; ++m)
#pragma unroll
      for (int n = 0; n < 4; ++n)
        acc[m][n] = MFMA16(af[m], bfr[n], acc[m][n]);
  }

#pragma unroll
  for (int m = 0; m < 4; ++m) {
    int row = bm + wr + m * 16 + ((lane >> 4) << 2);
#pragma unroll
    for (int n = 0; n < 4; ++n) {
      int col = bn + wc + n * 16 + (lane & 15);
#pragma unroll
      for (int j = 0; j < 4; ++j) {
        if (OUT_BF16) {
          ((u16*)Cout)[(size_t)(row + j) * N + col] = f2bf(acc[m][n][j]);
        } else {
          float bb = HAS_BIAS ? bias[col] : 0.f;
          ((float*)Cout)[(size_t)(row + j) * N + col] = acc[m][n][j] + bb;
        }
      }
    }
  }
}

// ---------------- q/k normalize, row per thread (vectorized, no shuffles) ----------------
__global__ __launch_bounds__(256) void k_qknorm(const u16* __restrict__ QKV,
                                                const float* __restrict__ logit_scale,
                                                u16* __restrict__ Qn, u16* __restrict__ Kn) {
  int idx = blockIdx.x * 256 + threadIdx.x;   // 65536 = 2*16*2048 rows
  int n = idx & 2047, bh = idx >> 11;
  int b = bh >> 4, h = bh & 15;
  float scale = __expf(fminf(logit_scale[h], MAXLOG));
  const u16* qp = QKV + ((size_t)(b * 2048 + n)) * 3072 + h * 64;
  bf16x8 qv[8], kv[8];
#pragma unroll
  for (int j = 0; j < 8; ++j) {
    qv[j] = *(const bf16x8*)(qp + j * 8);
    kv[j] = *(const bf16x8*)(qp + 1024 + j * 8);
  }
  float sq = 0.f, sk = 0.f;
#pragma unroll
  for (int j = 0; j < 8; ++j)
#pragma unroll
    for (int e = 0; e < 8; ++e) {
      float fq = bf2f((u16)qv[j][e]);
      float fk = bf2f((u16)kv[j][e]);
      sq += fq * fq;
      sk += fk * fk;
    }
  float rq = scale / fmaxf(sqrtf(sq), 1e-12f);
  float rk = 1.0f / fmaxf(sqrtf(sk), 1e-12f);
  u16* qo = Qn + ((size_t)bh * 2048 + n) * 64;
  u16* ko = Kn + ((size_t)bh * 2048 + n) * 64;
#pragma unroll
  for (int j = 0; j < 8; ++j) {
    bf16x8 oq, ok;
#pragma unroll
    for (int e = 0; e < 8; ++e) {
      oq[e] = (short)f2bf(bf2f((u16)qv[j][e]) * rq);
      ok[e] = (short)f2bf(bf2f((u16)kv[j][e]) * rk);
    }
    *(bf16x8*)(qo + j * 8) = oq;
    *(bf16x8*)(ko + j * 8) = ok;
  }
}

// ---------------- V transpose: QKV v-part [n][64] -> Vt [64][2048] per bh ----------------
__global__ __launch_bounds__(256) void k_vtrans(const u16* __restrict__ QKV,
                                                u16* __restrict__ Vt) {
  __shared__ u16 lds[64][72];
  int nt = blockIdx.x, h = blockIdx.y, b = blockIdx.z;
  int tid = threadIdx.x;
  int bh = b * 16 + h;
  int r = tid >> 2, cq = (tid & 3) << 4;
  size_t voff = ((size_t)(b * 2048 + nt * 64 + r)) * 3072 + 2048 + h * 64 + cq;
  *(bf16x8*)&lds[r][cq] = *(const bf16x8*)&QKV[voff];
  *(bf16x8*)&lds[r][cq + 8] = *(const bf16x8*)&QKV[voff + 8];
  __syncthreads();
  int d = tid >> 2, nq = (tid & 3) << 4;
  bf16x8 o0, o1;
#pragma unroll
  for (int i = 0; i < 8; ++i) o0[i] = (short)lds[nq + i][d];
#pragma unroll
  for (int i = 0; i < 8; ++i) o1[i] = (short)lds[nq + 8 + i][d];
  u16* vd = Vt + ((size_t)bh * 64 + d) * 2048 + nt * 64 + nq;
  *(bf16x8*)vd = o0;
  *(bf16x8*)(vd + 8) = o1;
}

// ---------------- flash attention (R7 structure: LDS dbuf, counted-vmcnt, raw barriers) ----------------
// No split-KV (combine kernel was net-negative: R2 vs R4/R7). grid (bh=32, qblk=16);
// blockIdx.x = bh pins each head's blocks to one XCD (K/V L2-resident, FETCH ~12MB).
__global__ __launch_bounds__(256, 2) void k_flash(const u16* __restrict__ Qn,
                                                  const u16* __restrict__ Kn,
                                                  const u16* __restrict__ Vt,
                                                  const float* __restrict__ logit_scale,
                                                  u16* __restrict__ AO) {
  __shared__ __align__(16) u16 lsK[2][64 * 64];
  __shared__ __align__(16) u16 lsV[2][64 * 64];
  __shared__ float l_s[4][32];
  int tid = threadIdx.x, lane = tid & 63, wave = tid >> 6;
  int r31 = lane & 31, h = lane >> 5;
  int bh = blockIdx.x, b = bh >> 4, hd = bh & 15;
  int qw = blockIdx.y * 128 + wave * 32;
  const u16* Q = Qn + (size_t)bh * 2048 * 64;
  const u16* Kb = Kn + (size_t)bh * 2048 * 64;
  const u16* Vb = Vt + (size_t)bh * 64 * 2048;

  float negC = -__expf(fminf(logit_scale[hd], MAXLOG));

  // Q B-fragments: col=lane&31=q, k(d) = 16*ks + 8*h + e
  bf16x8 qB[4];
#pragma unroll
  for (int ks = 0; ks < 4; ++ks)
    qB[ks] = *(const bf16x8*)&Q[(size_t)(qw + r31) * 64 + ks * 16 + h * 8];

  // staging offsets (pre-swizzled global source, linear LDS dest)
  size_t kGO[2], vGO[2];
  int lOff[2];
#pragma unroll
  for (int j = 0; j < 2; ++j) {
    int s = j * 256 + tid;
    int row = s >> 3, ch = s & 7, g = ch ^ (row & 7);
    kGO[j] = (size_t)row * 64 + g * 8;
    vGO[j] = (size_t)row * 2048 + g * 8;
    lOff[j] = s * 8;
  }

  // LDS read offsets (swizzled): rows a*32+r31, chunk (2*ks+h) ^ (r31&7)
  int off[2][4];
#pragma unroll
  for (int a = 0; a < 2; ++a)
#pragma unroll
    for (int ks = 0; ks < 4; ++ks)
      off[a][ks] = (a * 32 + r31) * 64 + ((((ks << 1) | h) ^ (r31 & 7)) << 3);

  f32x16 o0, o1;
#pragma unroll
  for (int i = 0; i < 16; ++i) { o0[i] = 0.f; o1[i] = 0.f; }
  float lsum = 0.f;

#define STAGE(dstbuf, kvt)                                          \
  {                                                                 \
    size_t kv0 = (size_t)(kvt) * 64;                                \
    gload16(Kb + kv0 * 64 + kGO[0], &lsK[dstbuf][lOff[0]]);         \
    gload16(Kb + kv0 * 64 + kGO[1], &lsK[dstbuf][lOff[1]]);         \
    gload16(Vb + kv0 + vGO[0], &lsV[dstbuf][lOff[0]]);              \
    gload16(Vb + kv0 + vGO[1], &lsV[dstbuf][lOff[1]]);              \
  }

  // prologue: stage tile 0 (no wait; first iteration's VMCNT covers it)
  STAGE(0, 0);

#pragma unroll 1
  for (int t = 0; t < 32; ++t) {
    int cur = t & 1;
    if (t < 31) {
      STAGE(cur ^ 1, t + 1);  // next tile's 4 loads: stay in flight across barrier
      VMCNT4();               // wait only the 4 older loads (tile t's staging)
    } else {
      VMCNT0();
    }
    rawbar();                 // buf[cur] ready for all waves
    const u16* Kl = lsK[cur];
    const u16* Vl = lsV[cur];

    // S^T = K Q^T - scale   (rows kv, cols q)
    f32x16 s0, s1;
#pragma unroll
    for (int i = 0; i < 16; ++i) { s0[i] = negC; s1[i] = negC; }
    bf16x8 k0f[4], k1f[4];
#pragma unroll
    for (int ks = 0; ks < 4; ++ks) {
      k0f[ks] = *(const bf16x8*)&Kl[off[0][ks]];
      k1f[ks] = *(const bf16x8*)&Kl[off[1][ks]];
    }
    __builtin_amdgcn_s_setprio(1);
#pragma unroll
    for (int ks = 0; ks < 4; ++ks) {
      s0 = MFMA32(k0f[ks], qB[ks], s0);
      s1 = MFMA32(k1f[ks], qB[ks], s1);
    }
    __builtin_amdgcn_s_setprio(0);

    // V fragments (LDS)
    bf16x8 v0f[4], v1f[4];
#pragma unroll
    for (int ks = 0; ks < 4; ++ks) {
      v0f[ks] = *(const bf16x8*)&Vl[off[0][ks]];
      v1f[ks] = *(const bf16x8*)&Vl[off[1][ks]];
    }

    // P = exp(S - scale), lane-local l accumulation (no max, no shuffles)
#pragma unroll
    for (int i = 0; i < 16; ++i) {
      float e0 = __expf(s0[i]);
      float e1 = __expf(s1[i]);
      lsum += e0 + e1;
      s0[i] = e0; s1[i] = e1;
    }

    // pack P rows into PV A-fragments: cvt_pk pairs + permlane32 half-swap
    bf16x8 pa[4];
    {
      u32 c0 = cvtpk(s0[0], s0[1]),  c1 = cvtpk(s0[2], s0[3]);
      u32 c2 = cvtpk(s0[4], s0[5]),  c3 = cvtpk(s0[6], s0[7]);
      u32 c4 = cvtpk(s0[8], s0[9]),  c5 = cvtpk(s0[10], s0[11]);
      u32 c6 = cvtpk(s0[12], s0[13]), c7 = cvtpk(s0[14], s0[15]);
      plswap(c0, c2); plswap(c1, c3); plswap(c4, c6); plswap(c5, c7);
      pa[0] = asbf((u32x4){c0, c1, c2, c3});
      pa[1] = asbf((u32x4){c4, c5, c6, c7});
      u32 d0 = cvtpk(s1[0], s1[1]),  d1 = cvtpk(s1[2], s1[3]);
      u32 d2 = cvtpk(s1[4], s1[5]),  d3 = cvtpk(s1[6], s1[7]);
      u32 d4 = cvtpk(s1[8], s1[9]),  d5 = cvtpk(s1[10], s1[11]);
      u32 d6 = cvtpk(s1[12], s1[13]), d7 = cvtpk(s1[14], s1[15]);
      plswap(d0, d2); plswap(d1, d3); plswap(d4, d6); plswap(d5, d7);
      pa[2] = asbf((u32x4){d0, d1, d2, d3});
      pa[3] = asbf((u32x4){d4, d5, d6, d7});
    }

    // O += P V
    __builtin_amdgcn_s_setprio(1);
#pragma unroll
    for (int ks = 0; ks < 4; ++ks) {
      o0 = MFMA32(pa[ks], v0f[ks], o0);
      o1 = MFMA32(pa[ks], v1f[ks], o1);
    }
    __builtin_amdgcn_s_setprio(0);

    rawbar();                 // all waves done reading buf[cur]; next STAGE may overwrite
  }
#undef STAGE

  // combine l across lane halves; redistribute per-q 1/l via LDS
  float ltot = lsum + __shfl_xor(lsum, 32, 64);
  if (h == 0) l_s[wave][r31] = 1.0f / ltot;
  __syncthreads();

#pragma unroll
  for (int r = 0; r < 16; ++r) {
    int cr = (r & 3) + ((r >> 2) << 3) + (h << 2);
    int qr = qw + cr;
    float li = l_s[wave][cr];
    size_t base = ((size_t)(b * 2048 + qr)) * 1024 + hd * 64;
    AO[base + r31] = f2bf(o0[r] * li);
    AO[base + 32 + r31] = f2bf(o1[r] * li);
  }
}

// ---------------- host ----------------
extern "C" void kernel_launch(void* const* d_in, const int* in_sizes, int n_in,
                              void* d_out, int out_size, void* d_ws, size_t ws_size,
                              hipStream_t stream) {
  const float* x = (const float*)d_in[0];
  const float* w_qkv = (const float*)d_in[1];
  const float* w_out = (const float*)d_in[2];
  const float* b_out = (const float*)d_in[3];
  const float* logit_scale = (const float*)d_in[4];

  char* ws = (char*)d_ws;
  u16* Xbf   = (u16*)(ws);                   // 8 MB  [4096][1024]
  u16* Wqkvt = (u16*)(ws + (8ll << 20));     // 6 MB  [3072][1024]
  u16* Woutt = (u16*)(ws + (14ll << 20));    // 2 MB  [1024][1024]
  u16* QKV   = (u16*)(ws + (16ll << 20));    // 24 MB [4096][3072]
  u16* Qn    = (u16*)(ws + (40ll << 20));    // 8 MB  [2][16][2048][64]
  u16* Kn    = (u16*)(ws + (48ll << 20));    // 8 MB
  u16* Vt    = (u16*)(ws + (56ll << 20));    // 8 MB  [2][16][64][2048]
  u16* AO    = Xbf;                          // reuse x-bf16 region [4096][1024]
  float* out = (float*)d_out;

  k_prep<<<3072, 256, 0, stream>>>(x, Xbf, w_qkv, Wqkvt, w_out, Woutt);
  k_gemm_bt<true, false><<<768, 256, 0, stream>>>(Xbf, Wqkvt, QKV, nullptr,
                                                  4096, 3072, 1024, 24);
  k_qknorm<<<256, 256, 0, stream>>>(QKV, logit_scale, Qn, Kn);
  k_vtrans<<<dim3(32, 16, 2), 256, 0, stream>>>(QKV, Vt);
  k_flash<<<dim3(32, 16), 256, 0, stream>>>(Qn, Kn, Vt, logit_scale, AO);
  k_gemm_bt<false, true><<<256, 256, 0, stream>>>(AO, Woutt, out, b_out,
                                                  4096, 1024, 1024, 8);
}

// Round 11
// 128.698 us; speedup vs baseline: 1.1967x; 1.0580x over previous
//
#include <hip/hip_runtime.h>

typedef __attribute__((ext_vector_type(8))) short bf16x8;
typedef __attribute__((ext_vector_type(4))) float f32x4;
typedef __attribute__((ext_vector_type(16))) float f32x16;
typedef unsigned short u16;
typedef unsigned int u32;
typedef __attribute__((ext_vector_type(4))) unsigned int u32x4;

#define DEV static __device__ __forceinline__

DEV u16 f2bf(float f) {
  u32 u = __float_as_uint(f);
  u += 0x7FFFu + ((u >> 16) & 1u);
  return (u16)(u >> 16);
}
DEV float bf2f(u16 h) { return __uint_as_float(((u32)h) << 16); }

DEV void gload16(const void* g, void* l) {
  __builtin_amdgcn_global_load_lds((const __attribute__((address_space(1))) void*)g,
                                   (__attribute__((address_space(3))) void*)l, 16, 0, 0);
}

#define MFMA16(a, b, c) __builtin_amdgcn_mfma_f32_16x16x32_bf16((a), (b), (c), 0, 0, 0)
#define MFMA32(a, b, c) __builtin_amdgcn_mfma_f32_32x32x16_bf16((a), (b), (c), 0, 0, 0)

DEV u32 cvtpk(float lo, float hi) {
  u32 r;
  asm("v_cvt_pk_bf16_f32 %0, %1, %2" : "=v"(r) : "v"(lo), "v"(hi));
  return r;
}
DEV void plswap(u32& a, u32& b) {
  asm volatile("v_permlane32_swap_b32 %0, %1" : "+v"(a), "+v"(b));
}
DEV bf16x8 asbf(u32x4 v) {
  union { u32x4 u; bf16x8 b; } x;
  x.u = v;
  return x.b;
}

// raw barrier with compiler fences: no implicit vmcnt drain (unlike __syncthreads)
DEV void rawbar() {
  __builtin_amdgcn_sched_barrier(0);
  asm volatile("" ::: "memory");
  __builtin_amdgcn_s_barrier();
  asm volatile("" ::: "memory");
  __builtin_amdgcn_sched_barrier(0);
}
#define VMCNT4() asm volatile("s_waitcnt vmcnt(4)" ::: "memory")
#define VMCNT0() asm volatile("s_waitcnt vmcnt(0)" ::: "memory")

#define MAXLOG 4.6051701859880914f

// ---------------- prep: x->bf16 cvt + both weight transposes (merged, 1 launch) ----------------
__global__ __launch_bounds__(256) void k_prep(const float* __restrict__ x,
                                              u16* __restrict__ Xbf,
                                              const float* __restrict__ w_qkv,
                                              u16* __restrict__ Wqkvt,
                                              const float* __restrict__ w_out,
                                              u16* __restrict__ Woutt) {
  __shared__ u16 lds[64][72];
  int blk = blockIdx.x;
  int t = threadIdx.x;
  if (blk < 2048) {
    int i = blk * 256 + t;
    const f32x4* p = (const f32x4*)(x + (size_t)i * 8);
    f32x4 a = p[0], b = p[1];
    bf16x8 o;
    o[0] = (short)f2bf(a[0]); o[1] = (short)f2bf(a[1]);
    o[2] = (short)f2bf(a[2]); o[3] = (short)f2bf(a[3]);
    o[4] = (short)f2bf(b[0]); o[5] = (short)f2bf(b[1]);
    o[6] = (short)f2bf(b[2]); o[7] = (short)f2bf(b[3]);
    *(bf16x8*)(Xbf + (size_t)i * 8) = o;
    return;
  }
  const float* src;
  u16* dst;
  int rows, cols, bx, by;
  if (blk < 2816) {
    int q = blk - 2048;          // 768 tiles: w_qkv 1024x3072 -> 3072x1024
    src = w_qkv; dst = Wqkvt; rows = 1024; cols = 3072;
    bx = q % 48; by = q / 48;
  } else {
    int q = blk - 2816;          // 256 tiles: w_out 1024x1024 -> 1024x1024
    src = w_out; dst = Woutt; rows = 1024; cols = 1024;
    bx = q % 16; by = q / 16;
  }
  int r0 = by * 64, c0 = bx * 64;
  int r = t >> 2, cq = (t & 3) << 4;
  const float* s = src + (size_t)(r0 + r) * cols + c0 + cq;
#pragma unroll
  for (int i = 0; i < 16; i += 4) {
    f32x4 v = *(const f32x4*)(s + i);
    lds[r][cq + i + 0] = f2bf(v[0]);
    lds[r][cq + i + 1] = f2bf(v[1]);
    lds[r][cq + i + 2] = f2bf(v[2]);
    lds[r][cq + i + 3] = f2bf(v[3]);
  }
  __syncthreads();
  int c = t >> 2, rq = (t & 3) << 4;
  bf16x8 o0, o1;
#pragma unroll
  for (int i = 0; i < 8; ++i) o0[i] = (short)lds[rq + i][c];
#pragma unroll
  for (int i = 0; i < 8; ++i) o1[i] = (short)lds[rq + 8 + i][c];
  u16* d = dst + (size_t)(c0 + c) * rows + r0 + rq;
  *(bf16x8*)d = o0;
  *(bf16x8*)(d + 8) = o1;
}

// ---------------- bf16 GEMM (128x128): C = A * Bt^T ----------------
// 1D grid with bijective XCD swizzle (nwg % 8 == 0): wg = (orig&7)*(nwg/8) + orig/8.
template <bool OUT_BF16, bool HAS_BIAS>
__global__ __launch_bounds__(256) void k_gemm_bt(const u16* __restrict__ A,
                                                 const u16* __restrict__ Bt,
                                                 void* __restrict__ Cout,
                                                 const float* __restrict__ bias,
                                                 int M, int N, int K, int nbx) {
  __shared__ __align__(16) u16 lsA[128 * 32];
  __shared__ __align__(16) u16 lsB[128 * 32];
  int tid = threadIdx.x;
  int lane = tid & 63, wave = tid >> 6;
  int wr = (wave >> 1) * 64, wc = (wave & 1) * 64;
  int nwg = gridDim.x;
  int orig = blockIdx.x;
  int wg = (orig & 7) * (nwg >> 3) + (orig >> 3);
  int bm = (wg / nbx) * 128, bn = (wg % nbx) * 128;

  f32x4 acc[4][4] = {};

  const u16* aSrc[2]; u16* aDst[2];
  const u16* bSrc[2]; u16* bDst[2];
#pragma unroll
  for (int j = 0; j < 2; ++j) {
    int s = wave * 128 + j * 64 + lane;
    int row = s >> 2, chunk = s & 3;
    int g = chunk ^ ((row >> 1) & 3);
    aSrc[j] = A + (size_t)(bm + row) * K + g * 8;
    bSrc[j] = Bt + (size_t)(bn + row) * K + g * 8;
    aDst[j] = &lsA[(wave * 128 + j * 64) * 8];
    bDst[j] = &lsB[(wave * 128 + j * 64) * 8];
  }

  for (int k0 = 0; k0 < K; k0 += 32) {
    __syncthreads();
    gload16(aSrc[0] + k0, aDst[0]);
    gload16(aSrc[1] + k0, aDst[1]);
    gload16(bSrc[0] + k0, bDst[0]);
    gload16(bSrc[1] + k0, bDst[1]);
    __syncthreads();
    bf16x8 af[4], bfr[4];
#pragma unroll
    for (int m = 0; m < 4; ++m) {
      int r = wr + m * 16 + (lane & 15);
      int p = (lane >> 4) ^ ((r >> 1) & 3);
      af[m] = *(const bf16x8*)&lsA[r * 32 + p * 8];
    }
#pragma unroll
    for (int n = 0; n < 4; ++n) {
      int r = wc + n * 16 + (lane & 15);
      int p = (lane >> 4) ^ ((r >> 1) & 3);
      bfr[n] = *(const bf16x8*)&lsB[r * 32 + p * 8];
    }
#pragma unroll
    for (int m = 0; m < 4; ++m)
#pragma unroll
      for (int n = 0; n < 4; ++n)
        acc[m][n] = MFMA16(af[m], bfr[n], acc[m][n]);
  }

#pragma unroll
  for (int m = 0; m < 4; ++m) {
    int row = bm + wr + m * 16 + ((lane >> 4) << 2);
#pragma unroll
    for (int n = 0; n < 4; ++n) {
      int col = bn + wc + n * 16 + (lane & 15);
#pragma unroll
      for (int j = 0; j < 4; ++j) {
        if (OUT_BF16) {
          ((u16*)Cout)[(size_t)(row + j) * N + col] = f2bf(acc[m][n][j]);
        } else {
          float bb = HAS_BIAS ? bias[col] : 0.f;
          ((float*)Cout)[(size_t)(row + j) * N + col] = acc[m][n][j] + bb;
        }
      }
    }
  }
}

// ---------------- out-proj GEMM (128x64 tiles -> 512 blocks, 2/CU) ----------------
// fp32 out + bias. Same single-buffer structure; acc[4][2] per wave (2x2 wave grid).
__global__ __launch_bounds__(256) void k_gemm_out(const u16* __restrict__ A,
                                                  const u16* __restrict__ Bt,
                                                  float* __restrict__ Cout,
                                                  const float* __restrict__ bias,
                                                  int M, int N, int K, int nbx) {
  __shared__ __align__(16) u16 lsA[128 * 32];
  __shared__ __align__(16) u16 lsB[64 * 32];
  int tid = threadIdx.x;
  int lane = tid & 63, wave = tid >> 6;
  int wr = (wave >> 1) * 64, wc = (wave & 1) * 32;
  int nwg = gridDim.x;
  int orig = blockIdx.x;
  int wg = (orig & 7) * (nwg >> 3) + (orig >> 3);
  int bm = (wg / nbx) * 128, bn = (wg % nbx) * 64;

  f32x4 acc[4][2] = {};

  const u16* aSrc[2]; u16* aDst[2];
  const u16* bSrc;    u16* bDst;
#pragma unroll
  for (int j = 0; j < 2; ++j) {
    int s = wave * 128 + j * 64 + lane;
    int row = s >> 2, chunk = s & 3;
    int g = chunk ^ ((row >> 1) & 3);
    aSrc[j] = A + (size_t)(bm + row) * K + g * 8;
    aDst[j] = &lsA[(wave * 128 + j * 64) * 8];
  }
  {
    int s = wave * 64 + lane;   // 256 chunks cover 64 rows x 32 cols
    int row = s >> 2, chunk = s & 3;
    int g = chunk ^ ((row >> 1) & 3);
    bSrc = Bt + (size_t)(bn + row) * K + g * 8;
    bDst = &lsB[(wave * 64) * 8];
  }

  for (int k0 = 0; k0 < K; k0 += 32) {
    __syncthreads();
    gload16(aSrc[0] + k0, aDst[0]);
    gload16(aSrc[1] + k0, aDst[1]);
    gload16(bSrc + k0, bDst);
    __syncthreads();
    bf16x8 af[4], bfr[2];
#pragma unroll
    for (int m = 0; m < 4; ++m) {
      int r = wr + m * 16 + (lane & 15);
      int p = (lane >> 4) ^ ((r >> 1) & 3);
      af[m] = *(const bf16x8*)&lsA[r * 32 + p * 8];
    }
#pragma unroll
    for (int n = 0; n < 2; ++n) {
      int r = wc + n * 16 + (lane & 15);
      int p = (lane >> 4) ^ ((r >> 1) & 3);
      bfr[n] = *(const bf16x8*)&lsB[r * 32 + p * 8];
    }
#pragma unroll
    for (int m = 0; m < 4; ++m)
#pragma unroll
      for (int n = 0; n < 2; ++n)
        acc[m][n] = MFMA16(af[m], bfr[n], acc[m][n]);
  }

#pragma unroll
  for (int m = 0; m < 4; ++m) {
    int row = bm + wr + m * 16 + ((lane >> 4) << 2);
#pragma unroll
    for (int n = 0; n < 2; ++n) {
      int col = bn + wc + n * 16 + (lane & 15);
      float bb = bias[col];
#pragma unroll
      for (int j = 0; j < 4; ++j)
        Cout[(size_t)(row + j) * N + col] = acc[m][n][j] + bb;
    }
  }
}

// ---------------- merged q/k-normalize (blocks 0-255) + V transpose (blocks 256-1279) ----------------
__global__ __launch_bounds__(256) void k_qkpack(const u16* __restrict__ QKV,
                                                const float* __restrict__ logit_scale,
                                                u16* __restrict__ Qn, u16* __restrict__ Kn,
                                                u16* __restrict__ Vt) {
  __shared__ u16 lds[64][72];
  int blk = blockIdx.x;
  int tid = threadIdx.x;
  if (blk < 256) {
    // qk-norm: row per thread, vectorized, no shuffles
    int idx = blk * 256 + tid;                 // 65536 = 2*16*2048 rows
    int n = idx & 2047, bh = idx >> 11;
    int b = bh >> 4, h = bh & 15;
    float scale = __expf(fminf(logit_scale[h], MAXLOG));
    const u16* qp = QKV + ((size_t)(b * 2048 + n)) * 3072 + h * 64;
    bf16x8 qv[8], kv[8];
#pragma unroll
    for (int j = 0; j < 8; ++j) {
      qv[j] = *(const bf16x8*)(qp + j * 8);
      kv[j] = *(const bf16x8*)(qp + 1024 + j * 8);
    }
    float sq = 0.f, sk = 0.f;
#pragma unroll
    for (int j = 0; j < 8; ++j)
#pragma unroll
      for (int e = 0; e < 8; ++e) {
        float fq = bf2f((u16)qv[j][e]);
        float fk = bf2f((u16)kv[j][e]);
        sq += fq * fq;
        sk += fk * fk;
      }
    float rq = scale / fmaxf(sqrtf(sq), 1e-12f);
    float rk = 1.0f / fmaxf(sqrtf(sk), 1e-12f);
    u16* qo = Qn + ((size_t)bh * 2048 + n) * 64;
    u16* ko = Kn + ((size_t)bh * 2048 + n) * 64;
#pragma unroll
    for (int j = 0; j < 8; ++j) {
      bf16x8 oq, ok;
#pragma unroll
      for (int e = 0; e < 8; ++e) {
        oq[e] = (short)f2bf(bf2f((u16)qv[j][e]) * rq);
        ok[e] = (short)f2bf(bf2f((u16)kv[j][e]) * rk);
      }
      *(bf16x8*)(qo + j * 8) = oq;
      *(bf16x8*)(ko + j * 8) = ok;
    }
    return;
  }
  // V transpose: 1024 tiles
  int q = blk - 256;
  int nt = q & 31, h = (q >> 5) & 15, b = q >> 9;
  int bh = b * 16 + h;
  int r = tid >> 2, cq = (tid & 3) << 4;
  size_t voff = ((size_t)(b * 2048 + nt * 64 + r)) * 3072 + 2048 + h * 64 + cq;
  *(bf16x8*)&lds[r][cq] = *(const bf16x8*)&QKV[voff];
  *(bf16x8*)&lds[r][cq + 8] = *(const bf16x8*)&QKV[voff + 8];
  __syncthreads();
  int d = tid >> 2, nq = (tid & 3) << 4;
  bf16x8 o0, o1;
#pragma unroll
  for (int i = 0; i < 8; ++i) o0[i] = (short)lds[nq + i][d];
#pragma unroll
  for (int i = 0; i < 8; ++i) o1[i] = (short)lds[nq + 8 + i][d];
  u16* vd = Vt + ((size_t)bh * 64 + d) * 2048 + nt * 64 + nq;
  *(bf16x8*)vd = o0;
  *(bf16x8*)(vd + 8) = o1;
}

// ---------------- flash attention (R10 structure, unchanged: best-known 50us) ----------------
__global__ __launch_bounds__(256, 2) void k_flash(const u16* __restrict__ Qn,
                                                  const u16* __restrict__ Kn,
                                                  const u16* __restrict__ Vt,
                                                  const float* __restrict__ logit_scale,
                                                  u16* __restrict__ AO) {
  __shared__ __align__(16) u16 lsK[2][64 * 64];
  __shared__ __align__(16) u16 lsV[2][64 * 64];
  __shared__ float l_s[4][32];
  int tid = threadIdx.x, lane = tid & 63, wave = tid >> 6;
  int r31 = lane & 31, h = lane >> 5;
  int bh = blockIdx.x, b = bh >> 4, hd = bh & 15;
  int qw = blockIdx.y * 128 + wave * 32;
  const u16* Q = Qn + (size_t)bh * 2048 * 64;
  const u16* Kb = Kn + (size_t)bh * 2048 * 64;
  const u16* Vb = Vt + (size_t)bh * 64 * 2048;

  float negC = -__expf(fminf(logit_scale[hd], MAXLOG));

  bf16x8 qB[4];
#pragma unroll
  for (int ks = 0; ks < 4; ++ks)
    qB[ks] = *(const bf16x8*)&Q[(size_t)(qw + r31) * 64 + ks * 16 + h * 8];

  size_t kGO[2], vGO[2];
  int lOff[2];
#pragma unroll
  for (int j = 0; j < 2; ++j) {
    int s = j * 256 + tid;
    int row = s >> 3, ch = s & 7, g = ch ^ (row & 7);
    kGO[j] = (size_t)row * 64 + g * 8;
    vGO[j] = (size_t)row * 2048 + g * 8;
    lOff[j] = s * 8;
  }

  int off[2][4];
#pragma unroll
  for (int a = 0; a < 2; ++a)
#pragma unroll
    for (int ks = 0; ks < 4; ++ks)
      off[a][ks] = (a * 32 + r31) * 64 + ((((ks << 1) | h) ^ (r31 & 7)) << 3);

  f32x16 o0, o1;
#pragma unroll
  for (int i = 0; i < 16; ++i) { o0[i] = 0.f; o1[i] = 0.f; }
  float lsum = 0.f;

#define STAGE(dstbuf, kvt)                                          \
  {                                                                 \
    size_t kv0 = (size_t)(kvt) * 64;                                \
    gload16(Kb + kv0 * 64 + kGO[0], &lsK[dstbuf][lOff[0]]);         \
    gload16(Kb + kv0 * 64 + kGO[1], &lsK[dstbuf][lOff[1]]);         \
    gload16(Vb + kv0 + vGO[0], &lsV[dstbuf][lOff[0]]);              \
    gload16(Vb + kv0 + vGO[1], &lsV[dstbuf][lOff[1]]);              \
  }

  STAGE(0, 0);

#pragma unroll 1
  for (int t = 0; t < 32; ++t) {
    int cur = t & 1;
    if (t < 31) {
      STAGE(cur ^ 1, t + 1);
      VMCNT4();
    } else {
      VMCNT0();
    }
    rawbar();
    const u16* Kl = lsK[cur];
    const u16* Vl = lsV[cur];

    f32x16 s0, s1;
#pragma unroll
    for (int i = 0; i < 16; ++i) { s0[i] = negC; s1[i] = negC; }
    bf16x8 k0f[4], k1f[4];
#pragma unroll
    for (int ks = 0; ks < 4; ++ks) {
      k0f[ks] = *(const bf16x8*)&Kl[off[0][ks]];
      k1f[ks] = *(const bf16x8*)&Kl[off[1][ks]];
    }
    __builtin_amdgcn_s_setprio(1);
#pragma unroll
    for (int ks = 0; ks < 4; ++ks) {
      s0 = MFMA32(k0f[ks], qB[ks], s0);
      s1 = MFMA32(k1f[ks], qB[ks], s1);
    }
    __builtin_amdgcn_s_setprio(0);

    bf16x8 v0f[4], v1f[4];
#pragma unroll
    for (int ks = 0; ks < 4; ++ks) {
      v0f[ks] = *(const bf16x8*)&Vl[off[0][ks]];
      v1f[ks] = *(const bf16x8*)&Vl[off[1][ks]];
    }

#pragma unroll
    for (int i = 0; i < 16; ++i) {
      float e0 = __expf(s0[i]);
      float e1 = __expf(s1[i]);
      lsum += e0 + e1;
      s0[i] = e0; s1[i] = e1;
    }

    bf16x8 pa[4];
    {
      u32 c0 = cvtpk(s0[0], s0[1]),  c1 = cvtpk(s0[2], s0[3]);
      u32 c2 = cvtpk(s0[4], s0[5]),  c3 = cvtpk(s0[6], s0[7]);
      u32 c4 = cvtpk(s0[8], s0[9]),  c5 = cvtpk(s0[10], s0[11]);
      u32 c6 = cvtpk(s0[12], s0[13]), c7 = cvtpk(s0[14], s0[15]);
      plswap(c0, c2); plswap(c1, c3); plswap(c4, c6); plswap(c5, c7);
      pa[0] = asbf((u32x4){c0, c1, c2, c3});
      pa[1] = asbf((u32x4){c4, c5, c6, c7});
      u32 d0 = cvtpk(s1[0], s1[1]),  d1 = cvtpk(s1[2], s1[3]);
      u32 d2 = cvtpk(s1[4], s1[5]),  d3 = cvtpk(s1[6], s1[7]);
      u32 d4 = cvtpk(s1[8], s1[9]),  d5 = cvtpk(s1[10], s1[11]);
      u32 d6 = cvtpk(s1[12], s1[13]), d7 = cvtpk(s1[14], s1[15]);
      plswap(d0, d2); plswap(d1, d3); plswap(d4, d6); plswap(d5, d7);
      pa[2] = asbf((u32x4){d0, d1, d2, d3});
      pa[3] = asbf((u32x4){d4, d5, d6, d7});
    }

    __builtin_amdgcn_s_setprio(1);
#pragma unroll
    for (int ks = 0; ks < 4; ++ks) {
      o0 = MFMA32(pa[ks], v0f[ks], o0);
      o1 = MFMA32(pa[ks], v1f[ks], o1);
    }
    __builtin_amdgcn_s_setprio(0);

    rawbar();
  }
#undef STAGE

  float ltot = lsum + __shfl_xor(lsum, 32, 64);
  if (h == 0) l_s[wave][r31] = 1.0f / ltot;
  __syncthreads();

#pragma unroll
  for (int r = 0; r < 16; ++r) {
    int cr = (r & 3) + ((r >> 2) << 3) + (h << 2);
    int qr = qw + cr;
    float li = l_s[wave][cr];
    size_t base = ((size_t)(b * 2048 + qr)) * 1024 + hd * 64;
    AO[base + r31] = f2bf(o0[r] * li);
    AO[base + 32 + r31] = f2bf(o1[r] * li);
  }
}

// ---------------- host ----------------
extern "C" void kernel_launch(void* const* d_in, const int* in_sizes, int n_in,
                              void* d_out, int out_size, void* d_ws, size_t ws_size,
                              hipStream_t stream) {
  const float* x = (const float*)d_in[0];
  const float* w_qkv = (const float*)d_in[1];
  const float* w_out = (const float*)d_in[2];
  const float* b_out = (const float*)d_in[3];
  const float* logit_scale = (const float*)d_in[4];

  char* ws = (char*)d_ws;
  u16* Xbf   = (u16*)(ws);                   // 8 MB  [4096][1024]
  u16* Wqkvt = (u16*)(ws + (8ll << 20));     // 6 MB  [3072][1024]
  u16* Woutt = (u16*)(ws + (14ll << 20));    // 2 MB  [1024][1024]
  u16* QKV   = (u16*)(ws + (16ll << 20));    // 24 MB [4096][3072]
  u16* Qn    = (u16*)(ws + (40ll << 20));    // 8 MB  [2][16][2048][64]
  u16* Kn    = (u16*)(ws + (48ll << 20));    // 8 MB
  u16* Vt    = (u16*)(ws + (56ll << 20));    // 8 MB  [2][16][64][2048]
  u16* AO    = Xbf;                          // reuse x-bf16 region [4096][1024]
  float* out = (float*)d_out;

  k_prep<<<3072, 256, 0, stream>>>(x, Xbf, w_qkv, Wqkvt, w_out, Woutt);
  k_gemm_bt<true, false><<<768, 256, 0, stream>>>(Xbf, Wqkvt, QKV, nullptr,
                                                  4096, 3072, 1024, 24);
  k_qkpack<<<1280, 256, 0, stream>>>(QKV, logit_scale, Qn, Kn, Vt);
  k_flash<<<dim3(32, 16), 256, 0, stream>>>(Qn, Kn, Vt, logit_scale, AO);
  k_gemm_out<<<512, 256, 0, stream>>>(AO, Woutt, out, b_out,
                                      4096, 1024, 1024, 16);
}

// Round 12
// 117.694 us; speedup vs baseline: 1.3085x; 1.0935x over previous
//
#include <hip/hip_runtime.h>

typedef __attribute__((ext_vector_type(8))) short bf16x8;
typedef __attribute__((ext_vector_type(4))) float f32x4;
typedef __attribute__((ext_vector_type(16))) float f32x16;
typedef unsigned short u16;
typedef unsigned int u32;
typedef __attribute__((ext_vector_type(4))) unsigned int u32x4;

#define DEV static __device__ __forceinline__

DEV u16 f2bf(float f) {
  u32 u = __float_as_uint(f);
  u += 0x7FFFu + ((u >> 16) & 1u);
  return (u16)(u >> 16);
}
DEV float bf2f(u16 h) { return __uint_as_float(((u32)h) << 16); }

DEV void gload16(const void* g, void* l) {
  __builtin_amdgcn_global_load_lds((const __attribute__((address_space(1))) void*)g,
                                   (__attribute__((address_space(3))) void*)l, 16, 0, 0);
}

#define MFMA16(a, b, c) __builtin_amdgcn_mfma_f32_16x16x32_bf16((a), (b), (c), 0, 0, 0)
#define MFMA32(a, b, c) __builtin_amdgcn_mfma_f32_32x32x16_bf16((a), (b), (c), 0, 0, 0)

DEV u32 cvtpk(float lo, float hi) {
  u32 r;
  asm("v_cvt_pk_bf16_f32 %0, %1, %2" : "=v"(r) : "v"(lo), "v"(hi));
  return r;
}
DEV void plswap(u32& a, u32& b) {
  asm volatile("v_permlane32_swap_b32 %0, %1" : "+v"(a), "+v"(b));
}
DEV bf16x8 asbf(u32x4 v) {
  union { u32x4 u; bf16x8 b; } x;
  x.u = v;
  return x.b;
}

// raw barrier with compiler fences: no implicit vmcnt drain (unlike __syncthreads)
DEV void rawbar() {
  __builtin_amdgcn_sched_barrier(0);
  asm volatile("" ::: "memory");
  __builtin_amdgcn_s_barrier();
  asm volatile("" ::: "memory");
  __builtin_amdgcn_sched_barrier(0);
}
#define VMCNT4() asm volatile("s_waitcnt vmcnt(4)" ::: "memory")
#define VMCNT0() asm volatile("s_waitcnt vmcnt(0)" ::: "memory")
#define LGKM0()  asm volatile("s_waitcnt lgkmcnt(0)" ::: "memory")

#define MAXLOG 4.6051701859880914f

// ---------------- prep: x->bf16 cvt + both weight transposes (merged, 1 launch) ----------------
__global__ __launch_bounds__(256) void k_prep(const float* __restrict__ x,
                                              u16* __restrict__ Xbf,
                                              const float* __restrict__ w_qkv,
                                              u16* __restrict__ Wqkvt,
                                              const float* __restrict__ w_out,
                                              u16* __restrict__ Woutt) {
  __shared__ u16 lds[64][72];
  int blk = blockIdx.x;
  int t = threadIdx.x;
  if (blk < 2048) {
    int i = blk * 256 + t;
    const f32x4* p = (const f32x4*)(x + (size_t)i * 8);
    f32x4 a = p[0], b = p[1];
    bf16x8 o;
    o[0] = (short)f2bf(a[0]); o[1] = (short)f2bf(a[1]);
    o[2] = (short)f2bf(a[2]); o[3] = (short)f2bf(a[3]);
    o[4] = (short)f2bf(b[0]); o[5] = (short)f2bf(b[1]);
    o[6] = (short)f2bf(b[2]); o[7] = (short)f2bf(b[3]);
    *(bf16x8*)(Xbf + (size_t)i * 8) = o;
    return;
  }
  const float* src;
  u16* dst;
  int rows, cols, bx, by;
  if (blk < 2816) {
    int q = blk - 2048;          // 768 tiles: w_qkv 1024x3072 -> 3072x1024
    src = w_qkv; dst = Wqkvt; rows = 1024; cols = 3072;
    bx = q % 48; by = q / 48;
  } else {
    int q = blk - 2816;          // 256 tiles: w_out 1024x1024 -> 1024x1024
    src = w_out; dst = Woutt; rows = 1024; cols = 1024;
    bx = q % 16; by = q / 16;
  }
  int r0 = by * 64, c0 = bx * 64;
  int r = t >> 2, cq = (t & 3) << 4;
  const float* s = src + (size_t)(r0 + r) * cols + c0 + cq;
#pragma unroll
  for (int i = 0; i < 16; i += 4) {
    f32x4 v = *(const f32x4*)(s + i);
    lds[r][cq + i + 0] = f2bf(v[0]);
    lds[r][cq + i + 1] = f2bf(v[1]);
    lds[r][cq + i + 2] = f2bf(v[2]);
    lds[r][cq + i + 3] = f2bf(v[3]);
  }
  __syncthreads();
  int c = t >> 2, rq = (t & 3) << 4;
  bf16x8 o0, o1;
#pragma unroll
  for (int i = 0; i < 8; ++i) o0[i] = (short)lds[rq + i][c];
#pragma unroll
  for (int i = 0; i < 8; ++i) o1[i] = (short)lds[rq + 8 + i][c];
  u16* d = dst + (size_t)(c0 + c) * rows + r0 + rq;
  *(bf16x8*)d = o0;
  *(bf16x8*)(d + 8) = o1;
}

// ---------------- QKV GEMM with FUSED epilogue: q/k row-norm -> Qn/Kn, V transpose -> Vt ----------------
// C tile = 128x128; each wave's 64-col group == one head's full d-dim (since bn%128==0,
// wc in {0,64}, d=64). q/k: per-row sumsq over head dims = acc reduce + 16-lane shfl_xor
// (rows live in lane>>4, untouched). v: wave-local LDS transpose (XOR-swizzled [32][64]
// slices in the now-free staging LDS) -> coalesced 16B stores to Vt. QKV never hits memory.
__global__ __launch_bounds__(256) void k_gemm_qkv(const u16* __restrict__ A,
                                                  const u16* __restrict__ Bt,
                                                  const float* __restrict__ logit_scale,
                                                  u16* __restrict__ Qn, u16* __restrict__ Kn,
                                                  u16* __restrict__ Vt,
                                                  int M, int N, int K, int nbx) {
  __shared__ __align__(16) u16 lsA[128 * 32];
  __shared__ __align__(16) u16 lsB[128 * 32];
  int tid = threadIdx.x;
  int lane = tid & 63, wave = tid >> 6;
  int wr = (wave >> 1) * 64, wc = (wave & 1) * 64;
  int nwg = gridDim.x;
  int orig = blockIdx.x;
  int wg = (orig & 7) * (nwg >> 3) + (orig >> 3);
  int bm = (wg / nbx) * 128, bn = (wg % nbx) * 128;

  f32x4 acc[4][4] = {};

  const u16* aSrc[2]; u16* aDst[2];
  const u16* bSrc[2]; u16* bDst[2];
#pragma unroll
  for (int j = 0; j < 2; ++j) {
    int s = wave * 128 + j * 64 + lane;
    int row = s >> 2, chunk = s & 3;
    int g = chunk ^ ((row >> 1) & 3);
    aSrc[j] = A + (size_t)(bm + row) * K + g * 8;
    bSrc[j] = Bt + (size_t)(bn + row) * K + g * 8;
    aDst[j] = &lsA[(wave * 128 + j * 64) * 8];
    bDst[j] = &lsB[(wave * 128 + j * 64) * 8];
  }

  for (int k0 = 0; k0 < K; k0 += 32) {
    __syncthreads();
    gload16(aSrc[0] + k0, aDst[0]);
    gload16(aSrc[1] + k0, aDst[1]);
    gload16(bSrc[0] + k0, bDst[0]);
    gload16(bSrc[1] + k0, bDst[1]);
    __syncthreads();
    bf16x8 af[4], bfr[4];
#pragma unroll
    for (int m = 0; m < 4; ++m) {
      int r = wr + m * 16 + (lane & 15);
      int p = (lane >> 4) ^ ((r >> 1) & 3);
      af[m] = *(const bf16x8*)&lsA[r * 32 + p * 8];
    }
#pragma unroll
    for (int n = 0; n < 4; ++n) {
      int r = wc + n * 16 + (lane & 15);
      int p = (lane >> 4) ^ ((r >> 1) & 3);
      bfr[n] = *(const bf16x8*)&lsB[r * 32 + p * 8];
    }
#pragma unroll
    for (int m = 0; m < 4; ++m)
#pragma unroll
      for (int n = 0; n < 4; ++n)
        acc[m][n] = MFMA16(af[m], bfr[n], acc[m][n]);
  }

  int colg = bn + wc;  // this wave's 64-col group base (one head's d-range)
  if (colg < 2048) {
    // ---- q/k: normalize rows over this head's 64 dims ----
    bool isQ = colg < 1024;
    int h = (colg >> 6) & 15;
    float scale = isQ ? __expf(fminf(logit_scale[h], MAXLOG)) : 1.0f;
    u16* dst = isQ ? Qn : Kn;
#pragma unroll
    for (int m = 0; m < 4; ++m) {
#pragma unroll
      for (int j = 0; j < 4; ++j) {
        float ss = 0.f;
#pragma unroll
        for (int n = 0; n < 4; ++n) ss += acc[m][n][j] * acc[m][n][j];
        ss += __shfl_xor(ss, 1, 64);
        ss += __shfl_xor(ss, 2, 64);
        ss += __shfl_xor(ss, 4, 64);
        ss += __shfl_xor(ss, 8, 64);
        float r = scale / fmaxf(sqrtf(ss), 1e-12f);
        int row = bm + wr + m * 16 + ((lane >> 4) << 2) + j;
        int b = row >> 11, tok = row & 2047;
        size_t base = ((size_t)(b * 16 + h) * 2048 + tok) * 64;
#pragma unroll
        for (int n = 0; n < 4; ++n)
          dst[base + n * 16 + (lane & 15)] = f2bf(acc[m][n][j] * r);
      }
    }
  } else {
    // ---- v: wave-local LDS transpose -> Vt[bh][d][tok] ----
    int h = ((colg - 2048) >> 6) & 15;
    __syncthreads();  // all waves done with staging LDS (block-uniform: whole block is v)
    u16* sl = (wave < 2 ? lsA : lsB) + (wave & 1) * 2048;  // [32][64] u16 slice
    int bb = bm >> 11, bmm = bm & 2047;
    size_t vbase = ((size_t)(bb * 16 + h) * 64) * 2048;
#pragma unroll
    for (int rr = 0; rr < 2; ++rr) {
      // store d-half (n = 2rr, 2rr+1), XOR-swizzled tok-chunks
#pragma unroll
      for (int nn = 0; nn < 2; ++nn) {
        int n = rr * 2 + nn;
        int d32 = nn * 16 + (lane & 15);
        int xr = (d32 & 7) << 3;
#pragma unroll
        for (int m = 0; m < 4; ++m)
#pragma unroll
          for (int j = 0; j < 4; ++j) {
            int tok = m * 16 + ((lane >> 4) << 2) + j;
            sl[d32 * 64 + (tok ^ xr)] = f2bf(acc[m][n][j]);
          }
      }
      LGKM0();
      // read back coalesced (per-lane b128 along tok) and store 16B to Vt
#pragma unroll
      for (int ri = 0; ri < 4; ++ri) {
        int li = ri * 64 + lane;
        int d32 = li >> 3, c = li & 7;
        int cx = c ^ (d32 & 7);
        bf16x8 v = *(const bf16x8*)&sl[d32 * 64 + cx * 8];
        size_t dsto = vbase + (size_t)(rr * 32 + d32) * 2048 + bmm + wr + c * 8;
        *(bf16x8*)&Vt[dsto] = v;
      }
      LGKM0();  // reads complete before next round overwrites the slice
    }
  }
}

// ---------------- out-proj GEMM (128x64 tiles -> 512 blocks, 2/CU) ----------------
__global__ __launch_bounds__(256) void k_gemm_out(const u16* __restrict__ A,
                                                  const u16* __restrict__ Bt,
                                                  float* __restrict__ Cout,
                                                  const float* __restrict__ bias,
                                                  int M, int N, int K, int nbx) {
  __shared__ __align__(16) u16 lsA[128 * 32];
  __shared__ __align__(16) u16 lsB[64 * 32];
  int tid = threadIdx.x;
  int lane = tid & 63, wave = tid >> 6;
  int wr = (wave >> 1) * 64, wc = (wave & 1) * 32;
  int nwg = gridDim.x;
  int orig = blockIdx.x;
  int wg = (orig & 7) * (nwg >> 3) + (orig >> 3);
  int bm = (wg / nbx) * 128, bn = (wg % nbx) * 64;

  f32x4 acc[4][2] = {};

  const u16* aSrc[2]; u16* aDst[2];
  const u16* bSrc;    u16* bDst;
#pragma unroll
  for (int j = 0; j < 2; ++j) {
    int s = wave * 128 + j * 64 + lane;
    int row = s >> 2, chunk = s & 3;
    int g = chunk ^ ((row >> 1) & 3);
    aSrc[j] = A + (size_t)(bm + row) * K + g * 8;
    aDst[j] = &lsA[(wave * 128 + j * 64) * 8];
  }
  {
    int s = wave * 64 + lane;
    int row = s >> 2, chunk = s & 3;
    int g = chunk ^ ((row >> 1) & 3);
    bSrc = Bt + (size_t)(bn + row) * K + g * 8;
    bDst = &lsB[(wave * 64) * 8];
  }

  for (int k0 = 0; k0 < K; k0 += 32) {
    __syncthreads();
    gload16(aSrc[0] + k0, aDst[0]);
    gload16(aSrc[1] + k0, aDst[1]);
    gload16(bSrc + k0, bDst);
    __syncthreads();
    bf16x8 af[4], bfr[2];
#pragma unroll
    for (int m = 0; m < 4; ++m) {
      int r = wr + m * 16 + (lane & 15);
      int p = (lane >> 4) ^ ((r >> 1) & 3);
      af[m] = *(const bf16x8*)&lsA[r * 32 + p * 8];
    }
#pragma unroll
    for (int n = 0; n < 2; ++n) {
      int r = wc + n * 16 + (lane & 15);
      int p = (lane >> 4) ^ ((r >> 1) & 3);
      bfr[n] = *(const bf16x8*)&lsB[r * 32 + p * 8];
    }
#pragma unroll
    for (int m = 0; m < 4; ++m)
#pragma unroll
      for (int n = 0; n < 2; ++n)
        acc[m][n] = MFMA16(af[m], bfr[n], acc[m][n]);
  }

#pragma unroll
  for (int m = 0; m < 4; ++m) {
    int row = bm + wr + m * 16 + ((lane >> 4) << 2);
#pragma unroll
    for (int n = 0; n < 2; ++n) {
      int col = bn + wc + n * 16 + (lane & 15);
      float bb = bias[col];
#pragma unroll
      for (int j = 0; j < 4; ++j)
        Cout[(size_t)(row + j) * N + col] = acc[m][n][j] + bb;
    }
  }
}

// ---------------- flash attention (R10 structure, unchanged: best-known 50us) ----------------
__global__ __launch_bounds__(256, 2) void k_flash(const u16* __restrict__ Qn,
                                                  const u16* __restrict__ Kn,
                                                  const u16* __restrict__ Vt,
                                                  const float* __restrict__ logit_scale,
                                                  u16* __restrict__ AO) {
  __shared__ __align__(16) u16 lsK[2][64 * 64];
  __shared__ __align__(16) u16 lsV[2][64 * 64];
  __shared__ float l_s[4][32];
  int tid = threadIdx.x, lane = tid & 63, wave = tid >> 6;
  int r31 = lane & 31, h = lane >> 5;
  int bh = blockIdx.x, b = bh >> 4, hd = bh & 15;
  int qw = blockIdx.y * 128 + wave * 32;
  const u16* Q = Qn + (size_t)bh * 2048 * 64;
  const u16* Kb = Kn + (size_t)bh * 2048 * 64;
  const u16* Vb = Vt + (size_t)bh * 64 * 2048;

  float negC = -__expf(fminf(logit_scale[hd], MAXLOG));

  bf16x8 qB[4];
#pragma unroll
  for (int ks = 0; ks < 4; ++ks)
    qB[ks] = *(const bf16x8*)&Q[(size_t)(qw + r31) * 64 + ks * 16 + h * 8];

  size_t kGO[2], vGO[2];
  int lOff[2];
#pragma unroll
  for (int j = 0; j < 2; ++j) {
    int s = j * 256 + tid;
    int row = s >> 3, ch = s & 7, g = ch ^ (row & 7);
    kGO[j] = (size_t)row * 64 + g * 8;
    vGO[j] = (size_t)row * 2048 + g * 8;
    lOff[j] = s * 8;
  }

  int off[2][4];
#pragma unroll
  for (int a = 0; a < 2; ++a)
#pragma unroll
    for (int ks = 0; ks < 4; ++ks)
      off[a][ks] = (a * 32 + r31) * 64 + ((((ks << 1) | h) ^ (r31 & 7)) << 3);

  f32x16 o0, o1;
#pragma unroll
  for (int i = 0; i < 16; ++i) { o0[i] = 0.f; o1[i] = 0.f; }
  float lsum = 0.f;

#define STAGE(dstbuf, kvt)                                          \
  {                                                                 \
    size_t kv0 = (size_t)(kvt) * 64;                                \
    gload16(Kb + kv0 * 64 + kGO[0], &lsK[dstbuf][lOff[0]]);         \
    gload16(Kb + kv0 * 64 + kGO[1], &lsK[dstbuf][lOff[1]]);         \
    gload16(Vb + kv0 + vGO[0], &lsV[dstbuf][lOff[0]]);              \
    gload16(Vb + kv0 + vGO[1], &lsV[dstbuf][lOff[1]]);              \
  }

  STAGE(0, 0);

#pragma unroll 1
  for (int t = 0; t < 32; ++t) {
    int cur = t & 1;
    if (t < 31) {
      STAGE(cur ^ 1, t + 1);
      VMCNT4();
    } else {
      VMCNT0();
    }
    rawbar();
    const u16* Kl = lsK[cur];
    const u16* Vl = lsV[cur];

    f32x16 s0, s1;
#pragma unroll
    for (int i = 0; i < 16; ++i) { s0[i] = negC; s1[i] = negC; }
    bf16x8 k0f[4], k1f[4];
#pragma unroll
    for (int ks = 0; ks < 4; ++ks) {
      k0f[ks] = *(const bf16x8*)&Kl[off[0][ks]];
      k1f[ks] = *(const bf16x8*)&Kl[off[1][ks]];
    }
    __builtin_amdgcn_s_setprio(1);
#pragma unroll
    for (int ks = 0; ks < 4; ++ks) {
      s0 = MFMA32(k0f[ks], qB[ks], s0);
      s1 = MFMA32(k1f[ks], qB[ks], s1);
    }
    __builtin_amdgcn_s_setprio(0);

    bf16x8 v0f[4], v1f[4];
#pragma unroll
    for (int ks = 0; ks < 4; ++ks) {
      v0f[ks] = *(const bf16x8*)&Vl[off[0][ks]];
      v1f[ks] = *(const bf16x8*)&Vl[off[1][ks]];
    }

#pragma unroll
    for (int i = 0; i < 16; ++i) {
      float e0 = __expf(s0[i]);
      float e1 = __expf(s1[i]);
      lsum += e0 + e1;
      s0[i] = e0; s1[i] = e1;
    }

    bf16x8 pa[4];
    {
      u32 c0 = cvtpk(s0[0], s0[1]),  c1 = cvtpk(s0[2], s0[3]);
      u32 c2 = cvtpk(s0[4], s0[5]),  c3 = cvtpk(s0[6], s0[7]);
      u32 c4 = cvtpk(s0[8], s0[9]),  c5 = cvtpk(s0[10], s0[11]);
      u32 c6 = cvtpk(s0[12], s0[13]), c7 = cvtpk(s0[14], s0[15]);
      plswap(c0, c2); plswap(c1, c3); plswap(c4, c6); plswap(c5, c7);
      pa[0] = asbf((u32x4){c0, c1, c2, c3});
      pa[1] = asbf((u32x4){c4, c5, c6, c7});
      u32 d0 = cvtpk(s1[0], s1[1]),  d1 = cvtpk(s1[2], s1[3]);
      u32 d2 = cvtpk(s1[4], s1[5]),  d3 = cvtpk(s1[6], s1[7]);
      u32 d4 = cvtpk(s1[8], s1[9]),  d5 = cvtpk(s1[10], s1[11]);
      u32 d6 = cvtpk(s1[12], s1[13]), d7 = cvtpk(s1[14], s1[15]);
      plswap(d0, d2); plswap(d1, d3); plswap(d4, d6); plswap(d5, d7);
      pa[2] = asbf((u32x4){d0, d1, d2, d3});
      pa[3] = asbf((u32x4){d4, d5, d6, d7});
    }

    __builtin_amdgcn_s_setprio(1);
#pragma unroll
    for (int ks = 0; ks < 4; ++ks) {
      o0 = MFMA32(pa[ks], v0f[ks], o0);
      o1 = MFMA32(pa[ks], v1f[ks], o1);
    }
    __builtin_amdgcn_s_setprio(0);

    rawbar();
  }
#undef STAGE

  float ltot = lsum + __shfl_xor(lsum, 32, 64);
  if (h == 0) l_s[wave][r31] = 1.0f / ltot;
  __syncthreads();

#pragma unroll
  for (int r = 0; r < 16; ++r) {
    int cr = (r & 3) + ((r >> 2) << 3) + (h << 2);
    int qr = qw + cr;
    float li = l_s[wave][cr];
    size_t base = ((size_t)(b * 2048 + qr)) * 1024 + hd * 64;
    AO[base + r31] = f2bf(o0[r] * li);
    AO[base + 32 + r31] = f2bf(o1[r] * li);
  }
}

// ---------------- host ----------------
extern "C" void kernel_launch(void* const* d_in, const int* in_sizes, int n_in,
                              void* d_out, int out_size, void* d_ws, size_t ws_size,
                              hipStream_t stream) {
  const float* x = (const float*)d_in[0];
  const float* w_qkv = (const float*)d_in[1];
  const float* w_out = (const float*)d_in[2];
  const float* b_out = (const float*)d_in[3];
  const float* logit_scale = (const float*)d_in[4];

  char* ws = (char*)d_ws;
  u16* Xbf   = (u16*)(ws);                   // 8 MB  [4096][1024]
  u16* Wqkvt = (u16*)(ws + (8ll << 20));     // 6 MB  [3072][1024]
  u16* Woutt = (u16*)(ws + (14ll << 20));    // 2 MB  [1024][1024]
  u16* Qn    = (u16*)(ws + (16ll << 20));    // 8 MB  [2][16][2048][64]
  u16* Kn    = (u16*)(ws + (24ll << 20));    // 8 MB
  u16* Vt    = (u16*)(ws + (32ll << 20));    // 8 MB  [2][16][64][2048]
  u16* AO    = Xbf;                          // reuse x-bf16 region [4096][1024]
  float* out = (float*)d_out;

  k_prep<<<3072, 256, 0, stream>>>(x, Xbf, w_qkv, Wqkvt, w_out, Woutt);
  k_gemm_qkv<<<768, 256, 0, stream>>>(Xbf, Wqkvt, logit_scale, Qn, Kn, Vt,
                                      4096, 3072, 1024, 24);
  k_flash<<<dim3(32, 16), 256, 0, stream>>>(Qn, Kn, Vt, logit_scale, AO);
  k_gemm_out<<<512, 256, 0, stream>>>(AO, Woutt, out, b_out,
                                      4096, 1024, 1024, 16);
}